// Round 18
// baseline (2447.541 us; speedup 1.0000x reference)
//
#include <hip/hip_runtime.h>

#define Hh 256
#define Ww 256
#define NB 4
#define NM 64
#define KP 7
#define HW (Hh*Ww)
#define NX (NB*HW)                 // 262144 xhat pixels
#define NZQ ((size_t)NB*NM*HW)     // 16777216 z pixels
#define PT 16                      // px tile (16x16)
#define TWH 22                     // PT + 6 halo
#define LDSH 24                    // padded stride
#define NST 2                      // staging slots/thread: ceil(22*22/256)

typedef unsigned short u16;
typedef unsigned int u32;

__device__ __forceinline__ float bf2f(u16 u) {
  union { u32 i; float f; } c; c.i = ((u32)u) << 16; return c.f;
}
__device__ __forceinline__ u16 f2bf(float f) {
  union { float f; u32 i; } c; c.f = f;
  return (u16)((c.i + 0x7FFFu + ((c.i >> 16) & 1u)) >> 16);   // RNE
}
__device__ __forceinline__ ushort2 pack2(float x, float y) {
  return make_ushort2(f2bf(x), f2bf(y));
}
__device__ __forceinline__ float2 unpack2(ushort2 u) {
  return make_float2(bf2f(u.x), bf2f(u.y));
}

__device__ __forceinline__ void cmac(float& ar, float& ai, float2 v, float wr, float wi) {
  ar = fmaf(v.x, wr, ar);
  ar = fmaf(-v.y, wi, ar);
  ai = fmaf(v.x, wi, ai);
  ai = fmaf(v.y, wr, ai);
}

// ---------------- mean over (C,H,W) per batch, complex ----------------
__global__ __launch_bounds__(256) void mean_stage1(
    const float* __restrict__ yre, const float* __restrict__ yim,
    float2* __restrict__ part) {
  int blk = blockIdx.x;           // 256 blocks: 64 per batch
  int b = blk >> 6, chunk = blk & 63;
  int tid = threadIdx.x;
  int base = b*HW + chunk*1024;
  float sr = 0.f, si = 0.f;
  #pragma unroll
  for (int j = 0; j < 4; ++j) {
    sr += yre[base + tid + j*256];
    si += yim[base + tid + j*256];
  }
  #pragma unroll
  for (int off = 32; off > 0; off >>= 1) {
    sr += __shfl_down(sr, off);
    si += __shfl_down(si, off);
  }
  __shared__ float2 red[4];
  if ((tid & 63) == 0) red[tid >> 6] = make_float2(sr, si);
  __syncthreads();
  if (tid == 0) {
    float2 a = red[0], b2 = red[1], c = red[2], d = red[3];
    part[blk] = make_float2(a.x + b2.x + c.x + d.x, a.y + b2.y + c.y + d.y);
  }
}

__global__ __launch_bounds__(256) void mean_stage2(
    const float2* __restrict__ part, float2* __restrict__ mean) {
  int tid = threadIdx.x;
  int b = tid >> 6, lane = tid & 63;
  float2 v = part[b*64 + lane];
  float sr = v.x, si = v.y;
  #pragma unroll
  for (int off = 32; off > 0; off >>= 1) {
    sr += __shfl_down(sr, off);
    si += __shfl_down(si, off);
  }
  if (lane == 0) mean[b] = make_float2(sr / (float)HW, si / (float)HW);
}

// ---------------- z0 = ST(conv(yp, A0), t[0,0]) — m-split, 16x16 tile ----------------
__global__ __launch_bounds__(256) void conv_first_kernel(
    const float* __restrict__ yre, const float* __restrict__ yim,
    const float2* __restrict__ mean,
    const float* __restrict__ Awre, const float* __restrict__ Awim,
    const float* __restrict__ t, ushort2* __restrict__ z) {
  int tid = threadIdx.x;
  int blk = blockIdx.x;                 // 2048 = ms + 2*(txi + 16*(tyi + 16*b))
  int ms  = blk & 1;
  int txi = (blk >> 1) & 15, tyi = (blk >> 5) & 15, b = (blk >> 9) & 3;
  int ty0 = tyi*PT, tx0 = txi*PT;
  int thy = tid >> 4, thx = tid & 15;

  __shared__ float2 tile[TWH][LDSH];
  float2 mb = mean[b];
  const float* re = yre + b*HW;
  const float* im = yim + b*HW;
  for (int i = tid; i < TWH*TWH; i += 256) {
    int rr = i / TWH, cc = i - rr*TWH;
    int gy = ty0 - 3 + rr, gx = tx0 - 3 + cc;
    float2 v = make_float2(0.f, 0.f);
    if ((unsigned)gy < Hh && (unsigned)gx < Ww) {
      int o = gy*Ww + gx;
      v.x = re[o] - mb.x;
      v.y = im[o] - mb.y;
    }
    tile[rr][cc] = v;
  }
  __syncthreads();

  ushort2* zb = z + ((size_t)b*NM << 16);
  size_t o = (size_t)(ty0 + thy)*Ww + tx0 + thx;
  int m0 = ms*32;
  #pragma unroll 1
  for (int mm = 0; mm < 32; mm += 2) {
    int m = m0 + mm;
    const float* wr0 = Awre + m*49;     // k = 0
    const float* wi0 = Awim + m*49;
    float ar0 = 0.f, ai0 = 0.f, ar1 = 0.f, ai1 = 0.f;
    #pragma unroll
    for (int ky = 0; ky < KP; ++ky) {
      #pragma unroll
      for (int kx = 0; kx < KP; ++kx) {
        int wo = ky*KP + kx;
        float2 v = tile[thy + ky][thx + kx];
        cmac(ar0, ai0, v, wr0[wo], wi0[wo]);
        cmac(ar1, ai1, v, wr0[49 + wo], wi0[49 + wo]);
      }
    }
    float t0 = t[m], t1 = t[m + 1];     // t[0,0,m]
    float a0 = sqrtf(ar0*ar0 + ai0*ai0);
    float f0 = fmaxf(a0 - t0, 0.f) / (a0 + 1e-16f);
    float a1 = sqrtf(ar1*ar1 + ai1*ai1);
    float f1 = fmaxf(a1 - t1, 0.f) / (a1 + 1e-16f);
    zb[((size_t)m << 16) + o]       = pack2(ar0*f0, ai0*f0);
    zb[((size_t)(m + 1) << 16) + o] = pack2(ar1*f1, ai1*f1);
  }
}

// ---------------- partial convT over 32 channels -> rpart[s*NB*HW + ...] ----------------
__global__ __launch_bounds__(256) void convT_part_kernel(
    const ushort2* __restrict__ z,
    const float* __restrict__ Bwre, const float* __restrict__ Bwim,
    int k, float2* __restrict__ rpart) {
  int tid = threadIdx.x;
  int blk = blockIdx.x;                 // 2048 = s + 2*(txi + 16*(tyi + 16*b))
  int s   = blk & 1;
  int txi = (blk >> 1) & 15, tyi = (blk >> 5) & 15, b = (blk >> 9) & 3;
  int ty0 = tyi*PT, tx0 = txi*PT;
  int thy = tid >> 4, thx = tid & 15;

  __shared__ float2 tile[2][TWH][LDSH];

  int srr[NST], scc[NST], soff[NST];
  bool sok[NST], sin[NST];
  #pragma unroll
  for (int j = 0; j < NST; ++j) {
    int i = tid + j*256;
    sin[j] = i < TWH*TWH;
    int rr = sin[j] ? i / TWH : 0;
    int cc = sin[j] ? i - rr*TWH : 0;
    int gy = ty0 - 3 + rr, gx = tx0 - 3 + cc;
    sok[j] = sin[j] && (unsigned)gy < Hh && (unsigned)gx < Ww;
    srr[j] = rr; scc[j] = cc;
    soff[j] = sok[j] ? gy*Ww + gx : 0;
  }

  const ushort2* zb = z + ((size_t)b*NM << 16);
  const float2 zero = make_float2(0.f, 0.f);
  int m0 = s*32;

  {
    const ushort2* zm = zb + ((size_t)m0 << 16);
    #pragma unroll
    for (int j = 0; j < NST; ++j)
      if (sin[j]) tile[0][srr[j]][scc[j]] = sok[j] ? unpack2(zm[soff[j]]) : zero;
  }
  __syncthreads();

  float ar = 0.f, ai = 0.f;
  #pragma unroll 1
  for (int mm = 0; mm < 32; ++mm) {
    int m = m0 + mm;
    int cur = mm & 1, nxt = cur ^ 1;
    ushort2 pf[NST];
    if (mm + 1 < 32) {
      const ushort2* zn = zb + ((size_t)(m + 1) << 16);
      #pragma unroll
      for (int j = 0; j < NST; ++j)
        pf[j] = sok[j] ? zn[soff[j]] : make_ushort2(0, 0);
    }
    const float* wr = Bwre + (k*NM + m)*49;
    const float* wi = Bwim + (k*NM + m)*49;
    #pragma unroll
    for (int ky = 0; ky < KP; ++ky) {
      #pragma unroll
      for (int kx = 0; kx < KP; ++kx) {
        float2 v = tile[cur][thy + 6 - ky][thx + 6 - kx];
        int wo = ky*KP + kx;
        cmac(ar, ai, v, wr[wo], wi[wo]);
      }
    }
    if (mm + 1 < 32) {
      #pragma unroll
      for (int j = 0; j < NST; ++j)
        if (sin[j]) tile[nxt][srr[j]][scc[j]] = sok[j] ? unpack2(pf[j]) : zero;
    }
    __syncthreads();
  }

  int o = (ty0 + thy)*Ww + tx0 + thx;
  rpart[(size_t)s*NB*HW + b*HW + o] = make_float2(ar, ai);
}

// ---------------- z = ST(z - conv(p0+p1-yp, A[k]), t[k,0]) — m-split ----------------
__global__ __launch_bounds__(256) void conv_update_kernel(
    const float2* __restrict__ rpart,
    const float* __restrict__ yre, const float* __restrict__ yim,
    const float2* __restrict__ mean,
    const float* __restrict__ Awre, const float* __restrict__ Awim,
    const float* __restrict__ t, int k, ushort2* __restrict__ z) {
  int tid = threadIdx.x;
  int blk = blockIdx.x;
  int ms  = blk & 1;
  int txi = (blk >> 1) & 15, tyi = (blk >> 5) & 15, b = (blk >> 9) & 3;
  int ty0 = tyi*PT, tx0 = txi*PT;
  int thy = tid >> 4, thx = tid & 15;

  __shared__ float2 tile[TWH][LDSH];
  float2 mb = mean[b];
  for (int i = tid; i < TWH*TWH; i += 256) {
    int rr = i / TWH, cc = i - rr*TWH;
    int gy = ty0 - 3 + rr, gx = tx0 - 3 + cc;
    float2 v = make_float2(0.f, 0.f);
    if ((unsigned)gy < Hh && (unsigned)gx < Ww) {
      int o = b*HW + gy*Ww + gx;
      float2 p0 = rpart[o], p1 = rpart[(size_t)NB*HW + o];
      v.x = p0.x + p1.x - (yre[o] - mb.x);
      v.y = p0.y + p1.y - (yim[o] - mb.y);
    }
    tile[rr][cc] = v;
  }
  __syncthreads();

  const float* tw = t + k*2*NM;         // t[k,0,:]
  ushort2* zb = z + ((size_t)b*NM << 16);
  size_t o = (size_t)(ty0 + thy)*Ww + tx0 + thx;
  int m0 = ms*32;
  #pragma unroll 1
  for (int mm = 0; mm < 32; mm += 2) {
    int m = m0 + mm;
    const float* wr0 = Awre + (k*NM + m)*49;
    const float* wi0 = Awim + (k*NM + m)*49;
    float ar0 = 0.f, ai0 = 0.f, ar1 = 0.f, ai1 = 0.f;
    #pragma unroll
    for (int ky = 0; ky < KP; ++ky) {
      #pragma unroll
      for (int kx = 0; kx < KP; ++kx) {
        int wo = ky*KP + kx;
        float2 v = tile[thy + ky][thx + kx];
        cmac(ar0, ai0, v, wr0[wo], wi0[wo]);
        cmac(ar1, ai1, v, wr0[49 + wo], wi0[49 + wo]);
      }
    }
    size_t p0 = ((size_t)m << 16) + o, p1 = ((size_t)(m + 1) << 16) + o;
    float2 z0 = unpack2(zb[p0]);
    float2 z1 = unpack2(zb[p1]);
    float zr0 = z0.x - ar0, zi0 = z0.y - ai0;
    float zr1 = z1.x - ar1, zi1 = z1.y - ai1;
    float a0 = sqrtf(zr0*zr0 + zi0*zi0);
    float f0 = fmaxf(a0 - tw[m], 0.f) / (a0 + 1e-16f);
    float a1 = sqrtf(zr1*zr1 + zi1*zi1);
    float f1 = fmaxf(a1 - tw[m + 1], 0.f) / (a1 + 1e-16f);
    zb[p0] = pack2(zr0*f0, zi0*f0);
    zb[p1] = pack2(zr1*f1, zi1*f1);
  }
}

// ---------------- xhat partial reduce: xws = pack(x0 + x1 + mean) ----------------
__global__ __launch_bounds__(256) void xreduce_kernel(
    const float2* __restrict__ xpart,
    const float2* __restrict__ mean, ushort2* __restrict__ xws) {
  int p = blockIdx.x*256 + threadIdx.x;   // 0..NX
  int b = p >> 16;
  float2 mb = mean[b];
  float2 a = xpart[p], c = xpart[(size_t)NB*HW + p];
  xws[p] = pack2(a.x + c.x + mb.x, a.y + c.y + mb.y);
}

// ---------------- emit: shifted (+1 element) copy into d_out (R15/R16-proven) ----------------
__global__ __launch_bounds__(256) void emit_kernel(
    const ushort2* __restrict__ xws, const ushort2* __restrict__ zws,
    u16* __restrict__ out16) {
  size_t idx = (size_t)blockIdx.x*256 + threadIdx.x;
  ushort2* out2 = (ushort2*)out16;
  if (idx < (size_t)NX) {
    int p = (int)idx;
    ushort2 xp = xws[p];
    u16 nxt = (p + 1 < NX) ? xws[p + 1].x : zws[0].x;
    out2[p + 1] = make_ushort2(xp.y, nxt);
    if (p == 0) out16[1] = xp.x;
  } else {
    size_t q = idx - (size_t)NX;
    ushort2 zq = zws[q];
    if (q + 1 < NZQ) {
      out2[(size_t)262145 + q] = make_ushort2(zq.y, zws[q + 1].x);
    } else {
      out16[(size_t)2*NX + 2*NZQ] = zq.y;
    }
  }
}

extern "C" void kernel_launch(void* const* d_in, const int* in_sizes, int n_in,
                              void* d_out, int out_size, void* d_ws, size_t ws_size,
                              hipStream_t stream) {
  const float* yre  = (const float*)d_in[0];
  const float* yim  = (const float*)d_in[1];
  const float* Awre = (const float*)d_in[2];
  const float* Awim = (const float*)d_in[3];
  const float* Bwre = (const float*)d_in[4];
  const float* Bwim = (const float*)d_in[5];
  const float* t    = (const float*)d_in[6];

  // Working state in d_ws: z (64MB) + xhat (1MB), both interleaved bf16.
  ushort2* zws = (ushort2*)d_ws;
  ushort2* xws = (ushort2*)((char*)d_ws + (size_t)67108864);

  // Scratch in d_out head (all dead before emit):
  //   [0, 4MB)   : convT residual fp32 partials (2 splits x 4 batches x HW float2)
  //   [4MB, 8MB) : convT final fp32 partials
  //   [8MB,+32)  : mean ; [8MB+64, +2112) : part
  char* ob = (char*)d_out;
  float2* rpart = (float2*)ob;
  float2* xpart = (float2*)(ob + 4194304);
  float2* mean  = (float2*)(ob + 8388608);
  float2* part  = (float2*)(ob + 8388672);

  mean_stage1<<<256, 256, 0, stream>>>(yre, yim, part);
  mean_stage2<<<1, 256, 0, stream>>>(part, mean);

  dim3 grid2k(NB * (Hh/PT) * (Ww/PT) * 2);     // 2048 blocks
  conv_first_kernel<<<grid2k, 256, 0, stream>>>(yre, yim, mean, Awre, Awim, t, zws);
  for (int k = 1; k < 3; ++k) {
    convT_part_kernel<<<grid2k, 256, 0, stream>>>(zws, Bwre, Bwim, k, rpart);
    conv_update_kernel<<<grid2k, 256, 0, stream>>>(rpart, yre, yim, mean, Awre, Awim, t, k, zws);
  }
  convT_part_kernel<<<grid2k, 256, 0, stream>>>(zws, Bwre, Bwim, 0, xpart);
  xreduce_kernel<<<NX/256, 256, 0, stream>>>(xpart, mean, xws);

  size_t total = (size_t)NX + NZQ;
  emit_kernel<<<(unsigned)(total/256), 256, 0, stream>>>(xws, zws, (u16*)d_out);
}